// Round 1
// baseline (1007.006 us; speedup 1.0000x reference)
//
#include <hip/hip_runtime.h>
#include <hip/hip_bf16.h>

// Problem constants (fixed by the reference)
#define NB 4096
#define NT 200
#define ND 64
#define NH1 128
#define NH2 64

// ws float layout (after 256-byte header holding the dtype flag) — f32 path
#define WS_WX 0          // 128*128: rows 0..63 = W1b - W1c ; rows 64..127 = W1d
#define WS_WC 16384      // 64*128 : W1a + W1c
#define WS_W2 24576      // 128*64
#define WS_B1 32768      // 128
#define WS_B2 32896      // 64
#define WS_W3 32960      // 64
#define WS_B3 33024      // 1

// Batch-independent prep products for the bf16/MFMA path (module globals so we
// don't have to assume anything about ws_size).
__device__ __align__(16) float  g_wxt[8192];   // WxT[j][k] = W1b[k][j]-W1c[k][j]
__device__ __align__(16) float  g_wdt[8192];   // WdT[j][k] = W1d[k][j]
__device__ __align__(16) __bf16 g_w2ts[8192];  // W2T[j][k] bf16, XOR-swizzled

typedef __bf16 bf16x8 __attribute__((ext_vector_type(8)));
typedef float  f32x4  __attribute__((ext_vector_type(4)));

__device__ __forceinline__ float ldany(const void* p, int i, int bf) {
    if (bf) return __bfloat162float(((const __hip_bfloat16*)p)[i]);
    return ((const float*)p)[i];
}

// ---------------------------------------------------------------------------
// Prep: detect dtype (f32 vs bf16) from W1's bit patterns, then build the
// folded weight arrays in ws (f32 path) and device globals (bf16 path).
// ---------------------------------------------------------------------------
__global__ __launch_bounds__(256) void prep_kernel(
    const void* W1, const void* b1, const void* W2, const void* b2,
    const void* W3, const void* b3, int* flag_out, float* F) {
    __shared__ int votes;
    int tid = threadIdx.x;
    if (tid == 0) votes = 0;
    __syncthreads();
    {
        const unsigned* w1u = (const unsigned*)W1;
        unsigned w = w1u[tid];
        unsigned lo = w & 0xFFFFu;
        unsigned e = (lo >> 7) & 0xFFu;
        if (lo == 0u || (e >= 96u && e <= 124u)) atomicAdd(&votes, 1);
    }
    __syncthreads();
    int bf = (votes >= 160) ? 1 : 0;
    if (blockIdx.x == 0 && tid == 0) flag_out[0] = bf;

    int gtid = blockIdx.x * blockDim.x + tid;
    int gstride = gridDim.x * blockDim.x;

    for (int e = gtid; e < 8192; e += gstride) {
        int k = e >> 7, j = e & 127;
        float w1b = ldany(W1, (64 + k) * 128 + j, bf);
        float w1c = ldany(W1, (128 + k) * 128 + j, bf);
        float w1a = ldany(W1, k * 128 + j, bf);
        float w1d = ldany(W1, (192 + k) * 128 + j, bf);
        float wx = w1b - w1c;
        F[WS_WX + e] = wx;
        F[WS_WX + 8192 + e] = w1d;
        F[WS_WC + e] = w1a + w1c;
        g_wxt[j * 64 + k] = wx;
        g_wdt[j * 64 + k] = w1d;
        float w2v = ldany(W2, e, bf);
        F[WS_W2 + e] = w2v;
        int j2 = e & 63, k2 = e >> 6;  // W2 is [128][64] row-major
        g_w2ts[j2 * 128 + (k2 ^ ((j2 & 15) << 3))] = (__bf16)w2v;
    }
    for (int e = gtid; e < 128; e += gstride) F[WS_B1 + e] = ldany(b1, e, bf);
    for (int e = gtid; e < 64; e += gstride) {
        F[WS_B2 + e] = ldany(b2, e, bf);
        F[WS_W3 + e] = ldany(W3, e, bf);
    }
    if (gtid == 0) F[WS_B3] = ldany(b3, 0, bf);
}

// ---------------------------------------------------------------------------
// bf16 MFMA path. One block per batch element, 512 threads = 8 waves.
// Per wave: 16 output rows. GEMM1 (64->128) with per-batch Weff split hi/lo,
// GEMM2 (128->64) with h1 split hi/lo. All LDS tiles XOR-swizzled so the
// 16-lane column reads of ds_read_b128 are 2-way-or-free.
// ---------------------------------------------------------------------------
__device__ __forceinline__ void compute_chunk(
    int w, int lane, int tbase, int b, const int* mask,
    const __bf16* sH, const __bf16* sWhi, const __bf16* sWlo,
    const __bf16* sW2, __bf16* h1hi, __bf16* h1lo,
    const float* cbias, const float* b2s, const float* W3s, float b3v,
    float* ss)
{
    const int lq = lane >> 4, lr = lane & 15;
    const int t0 = 16 * w;

    // A fragments: h rows t0+lr, k = 32*s + lq*8 + e  (contiguous 8 per lane)
    const int ar = t0 + lr;
    const int asw = (ar & 7) << 3;
    const bf16x8 a0 = *(const bf16x8*)&sH[ar * 64 + ((lq * 8) ^ asw)];
    const bf16x8 a1 = *(const bf16x8*)&sH[ar * 64 + ((32 + lq * 8) ^ asw)];

    // GEMM1: h1[t][j] = relu(cbias[j] + sum_k h[t][k]*Weff[k][j]); Weff=hi+lo
#pragma unroll
    for (int n = 0; n < 8; n++) {
        const int col = n * 16 + lr;
        const int bsw = (col & 7) << 3;
        const int wb = col * 64;
        const float cb = cbias[col];
        f32x4 c = {cb, cb, cb, cb};
        c = __builtin_amdgcn_mfma_f32_16x16x32_bf16(
                a0, *(const bf16x8*)&sWhi[wb + ((lq * 8) ^ bsw)], c, 0, 0, 0);
        c = __builtin_amdgcn_mfma_f32_16x16x32_bf16(
                a1, *(const bf16x8*)&sWhi[wb + ((32 + lq * 8) ^ bsw)], c, 0, 0, 0);
        c = __builtin_amdgcn_mfma_f32_16x16x32_bf16(
                a0, *(const bf16x8*)&sWlo[wb + ((lq * 8) ^ bsw)], c, 0, 0, 0);
        c = __builtin_amdgcn_mfma_f32_16x16x32_bf16(
                a1, *(const bf16x8*)&sWlo[wb + ((32 + lq * 8) ^ bsw)], c, 0, 0, 0);
        // relu + hi/lo split into per-wave h1 buffer (C/D: row=4*lq+r, col=lr)
#pragma unroll
        for (int r = 0; r < 4; r++) {
            const int row = lq * 4 + r;
            const int hoff = row * 128 + (col ^ ((row & 15) << 3));
            float v = fmaxf(c[r], 0.f);
            __bf16 hi = (__bf16)v;
            h1hi[hoff] = hi;
            h1lo[hoff] = (__bf16)(v - (float)hi);
        }
    }

    // GEMM2: h2[t][j] = relu(b2[j] + sum_k h1[t][k]*W2[k][j])
    f32x4 acc2[4];
#pragma unroll
    for (int n = 0; n < 4; n++) {
        const float bb = b2s[n * 16 + lr];
        acc2[n] = (f32x4){bb, bb, bb, bb};
    }
    const int a2sw = lr << 3;
#pragma unroll
    for (int s = 0; s < 4; s++) {
        const int k0 = s * 32 + lq * 8;
        const bf16x8 ah = *(const bf16x8*)&h1hi[lr * 128 + (k0 ^ a2sw)];
        const bf16x8 al = *(const bf16x8*)&h1lo[lr * 128 + (k0 ^ a2sw)];
#pragma unroll
        for (int n = 0; n < 4; n++) {
            const int col = n * 16 + lr;
            const bf16x8 bb =
                *(const bf16x8*)&sW2[col * 128 + (k0 ^ ((col & 15) << 3))];
            acc2[n] = __builtin_amdgcn_mfma_f32_16x16x32_bf16(ah, bb, acc2[n], 0, 0, 0);
            acc2[n] = __builtin_amdgcn_mfma_f32_16x16x32_bf16(al, bb, acc2[n], 0, 0, 0);
        }
    }

    // scores: s[t] = b3 + sum_j relu(h2[t][j]) * W3[j]; reduce over lr group
#pragma unroll
    for (int r = 0; r < 4; r++) {
        float p = 0.f;
#pragma unroll
        for (int n = 0; n < 4; n++)
            p = fmaf(fmaxf(acc2[n][r], 0.f), W3s[n * 16 + lr], p);
        p += __shfl_xor(p, 1);
        p += __shfl_xor(p, 2);
        p += __shfl_xor(p, 4);
        p += __shfl_xor(p, 8);
        const int gt = tbase + t0 + lq * 4 + r;
        if (lr == 0 && gt < NT)
            ss[gt] = (mask[(long)b * NT + gt] != 0) ? (p + b3v) : -1e9f;
    }
}

__global__ __launch_bounds__(512) void attn_bf16_kernel(
    const void* cand, const void* hist, const int* mask,
    const int* flag_p, const float* F, void* out)
{
    if (flag_p[0] == 0) return;  // uniform: whole block exits (f32 path)

    __shared__ __align__(16) __bf16 sWhi[8192];   // WeffT hi [128][64] swz
    __shared__ __align__(16) __bf16 sWlo[8192];   // WeffT lo
    __shared__ __align__(16) __bf16 sW2[8192];    // W2T [64][128] swz
    __shared__ __align__(16) __bf16 sH[8192];     // h chunk [128][64] swz
    __shared__ __align__(16) __bf16 sH1[32768];   // per-wave h1 hi/lo [16][128]
    __shared__ float cbias[128];
    __shared__ float cs[64], W3s[64], b2s[64];
    __shared__ float ss[NT];
    __shared__ float sred[8];
    __shared__ float part[8 * 65];
    __shared__ float b3s;

    const int tid = threadIdx.x;
    const int b = blockIdx.x;
    const int w = tid >> 6, lane = tid & 63;
    const __hip_bfloat16* hp = (const __hip_bfloat16*)hist;

    // ---- phase A: small loads, W2T copy (pre-swizzled), stage chunk0 ----
    if (tid < 64) {
        cs[tid] = __bfloat162float(((const __hip_bfloat16*)cand)[(long)b * 64 + tid]);
        W3s[tid] = F[WS_W3 + tid];
        b2s[tid] = F[WS_B2 + tid];
    }
    if (tid == 0) b3s = F[WS_B3];
    *(uint4*)((char*)sW2 + tid * 16) =
        *(const uint4*)((const char*)g_w2ts + tid * 16);
    *(uint4*)((char*)sW2 + 8192 + tid * 16) =
        *(const uint4*)((const char*)g_w2ts + 8192 + tid * 16);
#pragma unroll
    for (int i = 0; i < 2; i++) {
        const int idx = tid + i * 512;
        const int t = idx >> 3, q = idx & 7;
        uint4 v = *(const uint4*)(hp + ((long)b * NT + t) * 64 + q * 8);
        *(uint4*)&sH[t * 64 + ((q * 8) ^ ((t & 7) << 3))] = v;
    }
    __syncthreads();

    // ---- phase B: build Weff hi/lo, cbias; issue chunk1 prefetch ----
#pragma unroll
    for (int i = 0; i < 16; i++) {
        const int e = tid + i * 512;
        const int j = e >> 6, k = e & 63;
        float wv = fmaf(cs[k], g_wdt[e], g_wxt[e]);
        __bf16 hi = (__bf16)wv;
        const int off = j * 64 + (k ^ ((j & 7) << 3));
        sWhi[off] = hi;
        sWlo[off] = (__bf16)(wv - (float)hi);
    }
    {   // cbias[j] = b1[j] + sum_k c[k]*Wc[k][j], 4 threads per j
        const int j = tid >> 2, kq = (tid & 3) << 4;
        float a = 0.f;
#pragma unroll
        for (int k2 = 0; k2 < 16; k2++)
            a = fmaf(cs[kq + k2], F[WS_WC + (kq + k2) * 128 + j], a);
        a += __shfl_xor(a, 1);
        a += __shfl_xor(a, 2);
        if ((tid & 3) == 0) cbias[j] = a + F[WS_B1 + j];
    }
    // chunk1 (rows 128..199) prefetch into registers; lands during chunk0 compute
    uint4 c1a, c1b = {0, 0, 0, 0};
    {
        const int t = 128 + (tid >> 3), q = tid & 7;
        c1a = *(const uint4*)(hp + ((long)b * NT + t) * 64 + q * 8);
    }
    if (tid < 64) {
        const int t = 192 + (tid >> 3), q = tid & 7;
        c1b = *(const uint4*)(hp + ((long)b * NT + t) * 64 + q * 8);
    }
    __builtin_amdgcn_sched_barrier(0);
    __syncthreads();

    const float b3v = b3s;
    // ---- chunk 0: rows 0..127, all 8 waves ----
    compute_chunk(w, lane, 0, b, mask, sH, sWhi, sWlo, sW2,
                  &sH1[w * 4096], &sH1[w * 4096 + 2048],
                  cbias, b2s, W3s, b3v, ss);
    __syncthreads();

    // ---- write chunk1 into sH (rows 128..199 + zero pad to 207) ----
    {
        const int t = tid >> 3, q = tid & 7;
        *(uint4*)&sH[t * 64 + ((q * 8) ^ ((t & 7) << 3))] = c1a;
    }
    if (tid < 64) {
        const int t = 64 + (tid >> 3), q = tid & 7;
        *(uint4*)&sH[t * 64 + ((q * 8) ^ ((t & 7) << 3))] = c1b;
    }
    if (tid < 64) {
        const int t = 72 + (tid >> 3), q = tid & 7;
        uint4 z = {0, 0, 0, 0};
        *(uint4*)&sH[t * 64 + ((q * 8) ^ ((t & 7) << 3))] = z;
    }
    __syncthreads();

    // ---- chunk 1: rows 128..199, waves 0..4 ----
    if (w < 5)
        compute_chunk(w, lane, 128, b, mask, sH, sWhi, sWlo, sW2,
                      &sH1[w * 4096], &sH1[w * 4096 + 2048],
                      cbias, b2s, W3s, b3v, ss);
    __syncthreads();

    // ---- softmax over ss[0..199] (shfl-based, 2 barriers) ----
    float v = (tid < NT) ? ss[tid] : -3.0e38f;
    if (tid < 256) {
        float m = v;
#pragma unroll
        for (int o = 32; o; o >>= 1) m = fmaxf(m, __shfl_xor(m, o));
        if ((tid & 63) == 0) sred[tid >> 6] = m;
    }
    __syncthreads();
    const float M = fmaxf(fmaxf(sred[0], sred[1]), fmaxf(sred[2], sred[3]));
    float p = (tid < NT) ? __expf(v - M) : 0.f;
    if (tid < 256) {
        float s2 = p;
#pragma unroll
        for (int o = 32; o; o >>= 1) s2 += __shfl_xor(s2, o);
        if ((tid & 63) == 0) sred[4 + (tid >> 6)] = s2;
    }
    __syncthreads();
    const float S = sred[4] + sred[5] + sred[6] + sred[7];
    if (tid < NT) ss[tid] = p / S;
    __syncthreads();

    // ---- out[b][d] = sum_t w[t] * hist[b][t][d] ----
    const int d = tid & 63, g = tid >> 6;
    float acc = 0.f;
    for (int t = g; t < NT; t += 8)
        acc = fmaf(ss[t], __bfloat162float(hp[((long)b * NT + t) * 64 + d]), acc);
    part[g * 65 + d] = acc;
    __syncthreads();
    if (tid < 64) {
        float o = 0.f;
#pragma unroll
        for (int g2 = 0; g2 < 8; g2++) o += part[g2 * 65 + tid];
        ((__hip_bfloat16*)out)[b * 64 + tid] = __float2bfloat16(o);
    }
}

// ---------------------------------------------------------------------------
// f32 fallback: the previous harness-verified VALU kernel, unchanged except
// for the early exit when inputs are bf16.
// ---------------------------------------------------------------------------
__global__ __launch_bounds__(512) void attn_f32_kernel(
    const void* cand, const void* hist, const int* mask,
    const int* flag_p, const float* F, void* out) {
    if (flag_p[0] != 0) return;
    __shared__ __align__(16) float Weff[64 * 128];
    __shared__ __align__(16) float W2s[128 * 64];
    __shared__ float htile[64 * 65];
    __shared__ float h1t[64 * 129];
    __shared__ float csh[64];
    __shared__ float cbias[128];
    __shared__ float W3s[64];
    __shared__ float b2s[64];
    __shared__ float ss[NT];
    __shared__ float red[512];
    __shared__ float part[8 * 65];
    __shared__ float b3s;

    const int tid = threadIdx.x;
    const int b = blockIdx.x;

    if (tid < 64) {
        csh[tid] = ((const float*)cand)[b * 64 + tid];
        W3s[tid] = F[WS_W3 + tid];
        b2s[tid] = F[WS_B2 + tid];
    }
    if (tid == 0) b3s = F[WS_B3];
    __syncthreads();

    if (tid < 128) {
        float a = F[WS_B1 + tid];
        for (int k = 0; k < 64; k++) a = fmaf(csh[k], F[WS_WC + k * 128 + tid], a);
        cbias[tid] = a;
    }
    for (int e = tid; e < 8192; e += 512) {
        int k = e >> 7;
        Weff[e] = fmaf(csh[k], F[WS_WX + 8192 + e], F[WS_WX + e]);
    }
    for (int e = tid; e < 8192; e += 512) W2s[e] = F[WS_W2 + e];
    __syncthreads();

    const int jg = tid & 31, tg = tid >> 5;
    const int j0 = jg * 4, t0r = tg * 4;
    const int jg2 = tid & 15, tg2 = tid >> 4;
    const int j20 = jg2 * 4, t20 = tg2 * 2;

    for (int tt = 0; tt < 4; tt++) {
        const int tbase = tt * 64;
        const int ntt = (tbase + 64 <= NT) ? 64 : (NT - tbase);
        {
            const float* hpp = (const float*)hist;
            for (int e = tid; e < ntt * 64; e += 512) {
                int t = e >> 6, k = e & 63;
                htile[t * 65 + k] = hpp[((long)(b * NT + tbase + t)) * 64 + k];
            }
        }
        __syncthreads();

        {
            float acc[4][4];
#pragma unroll
            for (int i = 0; i < 4; i++)
#pragma unroll
                for (int jj = 0; jj < 4; jj++) acc[i][jj] = cbias[j0 + jj];
            for (int k = 0; k < 64; k++) {
                const float4 wv = *(const float4*)&Weff[(k << 7) + j0];
                float x[4];
#pragma unroll
                for (int i = 0; i < 4; i++) x[i] = htile[(t0r + i) * 65 + k];
#pragma unroll
                for (int i = 0; i < 4; i++) {
                    acc[i][0] = fmaf(x[i], wv.x, acc[i][0]);
                    acc[i][1] = fmaf(x[i], wv.y, acc[i][1]);
                    acc[i][2] = fmaf(x[i], wv.z, acc[i][2]);
                    acc[i][3] = fmaf(x[i], wv.w, acc[i][3]);
                }
            }
#pragma unroll
            for (int i = 0; i < 4; i++)
#pragma unroll
                for (int jj = 0; jj < 4; jj++)
                    h1t[(t0r + i) * 129 + j0 + jj] = fmaxf(acc[i][jj], 0.f);
        }
        __syncthreads();

        {
            float a2[2][4];
#pragma unroll
            for (int i = 0; i < 2; i++)
#pragma unroll
                for (int jj = 0; jj < 4; jj++) a2[i][jj] = b2s[j20 + jj];
            for (int k = 0; k < 128; k++) {
                const float4 wv = *(const float4*)&W2s[(k << 6) + j20];
                float x0 = h1t[(t20 + 0) * 129 + k];
                float x1 = h1t[(t20 + 1) * 129 + k];
                a2[0][0] = fmaf(x0, wv.x, a2[0][0]);
                a2[0][1] = fmaf(x0, wv.y, a2[0][1]);
                a2[0][2] = fmaf(x0, wv.z, a2[0][2]);
                a2[0][3] = fmaf(x0, wv.w, a2[0][3]);
                a2[1][0] = fmaf(x1, wv.x, a2[1][0]);
                a2[1][1] = fmaf(x1, wv.y, a2[1][1]);
                a2[1][2] = fmaf(x1, wv.z, a2[1][2]);
                a2[1][3] = fmaf(x1, wv.w, a2[1][3]);
            }
#pragma unroll
            for (int i = 0; i < 2; i++)
#pragma unroll
                for (int jj = 0; jj < 4; jj++)
                    htile[(t20 + i) * 65 + j20 + jj] = fmaxf(a2[i][jj], 0.f);
        }
        __syncthreads();

        if (tid < ntt) {
            float s = b3s;
            for (int k = 0; k < 64; k++) s = fmaf(htile[tid * 65 + k], W3s[k], s);
            int m = mask[b * NT + tbase + tid];
            ss[tbase + tid] = (m != 0) ? s : -1e9f;
        }
        __syncthreads();
    }

    float v = (tid < NT) ? ss[tid] : -3.0e38f;
    red[tid] = v;
    __syncthreads();
    for (int s = 256; s > 0; s >>= 1) {
        if (tid < s) red[tid] = fmaxf(red[tid], red[tid + s]);
        __syncthreads();
    }
    float M = red[0];
    __syncthreads();
    float p = (tid < NT) ? __expf(ss[tid] - M) : 0.f;
    red[tid] = p;
    __syncthreads();
    for (int s = 256; s > 0; s >>= 1) {
        if (tid < s) red[tid] += red[tid + s];
        __syncthreads();
    }
    float S = red[0];
    if (tid < NT) ss[tid] = p / S;
    __syncthreads();

    const int d = tid & 63, g = tid >> 6;
    float acc = 0.f;
    {
        const float* hpp = (const float*)hist;
        for (int t = g; t < NT; t += 8)
            acc = fmaf(ss[t], hpp[((long)(b * NT + t)) * 64 + d], acc);
    }
    part[g * 65 + d] = acc;
    __syncthreads();
    if (tid < 64) {
        float o = 0.f;
#pragma unroll
        for (int g2 = 0; g2 < 8; g2++) o += part[g2 * 65 + tid];
        ((float*)out)[b * 64 + tid] = o;
    }
}

extern "C" void kernel_launch(void* const* d_in, const int* in_sizes, int n_in,
                              void* d_out, int out_size, void* d_ws, size_t ws_size,
                              hipStream_t stream) {
    const void* cand = d_in[0];
    const void* hist = d_in[1];
    const int* mask = (const int*)d_in[2];
    const void* W1 = d_in[3];
    const void* b1 = d_in[4];
    const void* W2 = d_in[5];
    const void* b2 = d_in[6];
    const void* W3 = d_in[7];
    const void* b3 = d_in[8];

    int* flag = (int*)d_ws;
    float* F = (float*)((char*)d_ws + 256);

    prep_kernel<<<32, 256, 0, stream>>>(W1, b1, W2, b2, W3, b3, flag, F);
    attn_f32_kernel<<<NB, 512, 0, stream>>>(cand, hist, mask, flag, F, d_out);
    attn_bf16_kernel<<<NB, 512, 0, stream>>>(cand, hist, mask, flag, F, d_out);
}

// Round 2
// 506.677 us; speedup vs baseline: 1.9875x; 1.9875x over previous
//
#include <hip/hip_runtime.h>
#include <hip/hip_bf16.h>

// Problem constants (fixed by the reference)
#define NB 4096
#define NT 200
#define ND 64
#define NH1 128
#define NH2 64

// ws float layout (after 256-byte header holding the dtype flag)
#define WS_WX 0          // 128*128: rows 0..63 = W1b - W1c ; rows 64..127 = W1d
#define WS_WC 16384      // 64*128 : W1a + W1c
#define WS_W2 24576      // 128*64
#define WS_B1 32768      // 128
#define WS_B2 32896      // 64
#define WS_W3 32960      // 64
#define WS_B3 33024      // 1

// Batch-independent prep products (module globals; no ws_size assumptions).
__device__ __align__(16) float  g_wxt[8192];    // WxT[j][k] = W1b[k][j]-W1c[k][j]
__device__ __align__(16) float  g_wdt[8192];    // WdT[j][k] = W1d[k][j]
__device__ __align__(16) __bf16 g_w2ts[8192];   // W2T bf16 swizzled (bf16 path)
__device__ __align__(16) __bf16 g_w2tsh[8192];  // W2T hi (f32 path)
__device__ __align__(16) __bf16 g_w2tsl[8192];  // W2T lo (f32 path)

typedef __bf16 bf16x8 __attribute__((ext_vector_type(8)));
typedef __bf16 bf16x4 __attribute__((ext_vector_type(4)));
typedef float  f32x4  __attribute__((ext_vector_type(4)));

__device__ __forceinline__ float ldany(const void* p, int i, int bf) {
    if (bf) return __bfloat162float(((const __hip_bfloat16*)p)[i]);
    return ((const float*)p)[i];
}

// ---------------------------------------------------------------------------
// Prep: detect dtype, build folded weights (f32 in ws; transposed/split in
// device globals for the MFMA kernels).
// ---------------------------------------------------------------------------
__global__ __launch_bounds__(256) void prep_kernel(
    const void* W1, const void* b1, const void* W2, const void* b2,
    const void* W3, const void* b3, int* flag_out, float* F) {
    __shared__ int votes;
    int tid = threadIdx.x;
    if (tid == 0) votes = 0;
    __syncthreads();
    {
        const unsigned* w1u = (const unsigned*)W1;
        unsigned w = w1u[tid];
        unsigned lo = w & 0xFFFFu;
        unsigned e = (lo >> 7) & 0xFFu;
        if (lo == 0u || (e >= 96u && e <= 124u)) atomicAdd(&votes, 1);
    }
    __syncthreads();
    int bf = (votes >= 160) ? 1 : 0;
    if (blockIdx.x == 0 && tid == 0) flag_out[0] = bf;

    int gtid = blockIdx.x * blockDim.x + tid;
    int gstride = gridDim.x * blockDim.x;

    for (int e = gtid; e < 8192; e += gstride) {
        int k = e >> 7, j = e & 127;
        float w1b = ldany(W1, (64 + k) * 128 + j, bf);
        float w1c = ldany(W1, (128 + k) * 128 + j, bf);
        float w1a = ldany(W1, k * 128 + j, bf);
        float w1d = ldany(W1, (192 + k) * 128 + j, bf);
        float wx = w1b - w1c;
        F[WS_WX + e] = wx;
        F[WS_WX + 8192 + e] = w1d;
        F[WS_WC + e] = w1a + w1c;
        g_wxt[j * 64 + k] = wx;
        g_wdt[j * 64 + k] = w1d;
        float w2v = ldany(W2, e, bf);
        F[WS_W2 + e] = w2v;
        int j2 = e & 63, k2 = e >> 6;  // W2 is [128][64] row-major
        int so = j2 * 128 + (k2 ^ ((j2 & 15) << 3));
        g_w2ts[so] = (__bf16)w2v;
        __bf16 w2h = (__bf16)w2v;
        g_w2tsh[so] = w2h;
        g_w2tsl[so] = (__bf16)(w2v - (float)w2h);
    }
    for (int e = gtid; e < 128; e += gstride) F[WS_B1 + e] = ldany(b1, e, bf);
    for (int e = gtid; e < 64; e += gstride) {
        F[WS_B2 + e] = ldany(b2, e, bf);
        F[WS_W3 + e] = ldany(W3, e, bf);
    }
    if (gtid == 0) F[WS_B3] = ldany(b3, 0, bf);
}

// ===========================================================================
// bf16 MFMA path — UNCHANGED from the harness-verified round-1 kernel.
// ===========================================================================
__device__ __forceinline__ void compute_chunk(
    int w, int lane, int tbase, int b, const int* mask,
    const __bf16* sH, const __bf16* sWhi, const __bf16* sWlo,
    const __bf16* sW2, __bf16* h1hi, __bf16* h1lo,
    const float* cbias, const float* b2s, const float* W3s, float b3v,
    float* ss)
{
    const int lq = lane >> 4, lr = lane & 15;
    const int t0 = 16 * w;

    const int ar = t0 + lr;
    const int asw = (ar & 7) << 3;
    const bf16x8 a0 = *(const bf16x8*)&sH[ar * 64 + ((lq * 8) ^ asw)];
    const bf16x8 a1 = *(const bf16x8*)&sH[ar * 64 + ((32 + lq * 8) ^ asw)];

#pragma unroll
    for (int n = 0; n < 8; n++) {
        const int col = n * 16 + lr;
        const int bsw = (col & 7) << 3;
        const int wb = col * 64;
        const float cb = cbias[col];
        f32x4 c = {cb, cb, cb, cb};
        c = __builtin_amdgcn_mfma_f32_16x16x32_bf16(
                a0, *(const bf16x8*)&sWhi[wb + ((lq * 8) ^ bsw)], c, 0, 0, 0);
        c = __builtin_amdgcn_mfma_f32_16x16x32_bf16(
                a1, *(const bf16x8*)&sWhi[wb + ((32 + lq * 8) ^ bsw)], c, 0, 0, 0);
        c = __builtin_amdgcn_mfma_f32_16x16x32_bf16(
                a0, *(const bf16x8*)&sWlo[wb + ((lq * 8) ^ bsw)], c, 0, 0, 0);
        c = __builtin_amdgcn_mfma_f32_16x16x32_bf16(
                a1, *(const bf16x8*)&sWlo[wb + ((32 + lq * 8) ^ bsw)], c, 0, 0, 0);
#pragma unroll
        for (int r = 0; r < 4; r++) {
            const int row = lq * 4 + r;
            const int hoff = row * 128 + (col ^ ((row & 15) << 3));
            float v = fmaxf(c[r], 0.f);
            __bf16 hi = (__bf16)v;
            h1hi[hoff] = hi;
            h1lo[hoff] = (__bf16)(v - (float)hi);
        }
    }

    f32x4 acc2[4];
#pragma unroll
    for (int n = 0; n < 4; n++) {
        const float bb = b2s[n * 16 + lr];
        acc2[n] = (f32x4){bb, bb, bb, bb};
    }
    const int a2sw = lr << 3;
#pragma unroll
    for (int s = 0; s < 4; s++) {
        const int k0 = s * 32 + lq * 8;
        const bf16x8 ah = *(const bf16x8*)&h1hi[lr * 128 + (k0 ^ a2sw)];
        const bf16x8 al = *(const bf16x8*)&h1lo[lr * 128 + (k0 ^ a2sw)];
#pragma unroll
        for (int n = 0; n < 4; n++) {
            const int col = n * 16 + lr;
            const bf16x8 bb =
                *(const bf16x8*)&sW2[col * 128 + (k0 ^ ((col & 15) << 3))];
            acc2[n] = __builtin_amdgcn_mfma_f32_16x16x32_bf16(ah, bb, acc2[n], 0, 0, 0);
            acc2[n] = __builtin_amdgcn_mfma_f32_16x16x32_bf16(al, bb, acc2[n], 0, 0, 0);
        }
    }

#pragma unroll
    for (int r = 0; r < 4; r++) {
        float p = 0.f;
#pragma unroll
        for (int n = 0; n < 4; n++)
            p = fmaf(fmaxf(acc2[n][r], 0.f), W3s[n * 16 + lr], p);
        p += __shfl_xor(p, 1);
        p += __shfl_xor(p, 2);
        p += __shfl_xor(p, 4);
        p += __shfl_xor(p, 8);
        const int gt = tbase + t0 + lq * 4 + r;
        if (lr == 0 && gt < NT)
            ss[gt] = (mask[(long)b * NT + gt] != 0) ? (p + b3v) : -1e9f;
    }
}

__global__ __launch_bounds__(512) void attn_bf16_kernel(
    const void* cand, const void* hist, const int* mask,
    const int* flag_p, const float* F, void* out)
{
    if (flag_p[0] == 0) return;

    __shared__ __align__(16) __bf16 sWhi[8192];
    __shared__ __align__(16) __bf16 sWlo[8192];
    __shared__ __align__(16) __bf16 sW2[8192];
    __shared__ __align__(16) __bf16 sH[8192];
    __shared__ __align__(16) __bf16 sH1[32768];
    __shared__ float cbias[128];
    __shared__ float cs[64], W3s[64], b2s[64];
    __shared__ float ss[NT];
    __shared__ float sred[8];
    __shared__ float part[8 * 65];
    __shared__ float b3s;

    const int tid = threadIdx.x;
    const int b = blockIdx.x;
    const int w = tid >> 6, lane = tid & 63;
    const __hip_bfloat16* hp = (const __hip_bfloat16*)hist;

    if (tid < 64) {
        cs[tid] = __bfloat162float(((const __hip_bfloat16*)cand)[(long)b * 64 + tid]);
        W3s[tid] = F[WS_W3 + tid];
        b2s[tid] = F[WS_B2 + tid];
    }
    if (tid == 0) b3s = F[WS_B3];
    *(uint4*)((char*)sW2 + tid * 16) =
        *(const uint4*)((const char*)g_w2ts + tid * 16);
    *(uint4*)((char*)sW2 + 8192 + tid * 16) =
        *(const uint4*)((const char*)g_w2ts + 8192 + tid * 16);
#pragma unroll
    for (int i = 0; i < 2; i++) {
        const int idx = tid + i * 512;
        const int t = idx >> 3, q = idx & 7;
        uint4 v = *(const uint4*)(hp + ((long)b * NT + t) * 64 + q * 8);
        *(uint4*)&sH[t * 64 + ((q * 8) ^ ((t & 7) << 3))] = v;
    }
    __syncthreads();

#pragma unroll
    for (int i = 0; i < 16; i++) {
        const int e = tid + i * 512;
        const int j = e >> 6, k = e & 63;
        float wv = fmaf(cs[k], g_wdt[e], g_wxt[e]);
        __bf16 hi = (__bf16)wv;
        const int off = j * 64 + (k ^ ((j & 7) << 3));
        sWhi[off] = hi;
        sWlo[off] = (__bf16)(wv - (float)hi);
    }
    {
        const int j = tid >> 2, kq = (tid & 3) << 4;
        float a = 0.f;
#pragma unroll
        for (int k2 = 0; k2 < 16; k2++)
            a = fmaf(cs[kq + k2], F[WS_WC + (kq + k2) * 128 + j], a);
        a += __shfl_xor(a, 1);
        a += __shfl_xor(a, 2);
        if ((tid & 3) == 0) cbias[j] = a + F[WS_B1 + j];
    }
    uint4 c1a, c1b = {0, 0, 0, 0};
    {
        const int t = 128 + (tid >> 3), q = tid & 7;
        c1a = *(const uint4*)(hp + ((long)b * NT + t) * 64 + q * 8);
    }
    if (tid < 64) {
        const int t = 192 + (tid >> 3), q = tid & 7;
        c1b = *(const uint4*)(hp + ((long)b * NT + t) * 64 + q * 8);
    }
    __builtin_amdgcn_sched_barrier(0);
    __syncthreads();

    const float b3v = b3s;
    compute_chunk(w, lane, 0, b, mask, sH, sWhi, sWlo, sW2,
                  &sH1[w * 4096], &sH1[w * 4096 + 2048],
                  cbias, b2s, W3s, b3v, ss);
    __syncthreads();

    {
        const int t = tid >> 3, q = tid & 7;
        *(uint4*)&sH[t * 64 + ((q * 8) ^ ((t & 7) << 3))] = c1a;
    }
    if (tid < 64) {
        const int t = 64 + (tid >> 3), q = tid & 7;
        *(uint4*)&sH[t * 64 + ((q * 8) ^ ((t & 7) << 3))] = c1b;
    }
    if (tid < 64) {
        const int t = 72 + (tid >> 3), q = tid & 7;
        uint4 z = {0, 0, 0, 0};
        *(uint4*)&sH[t * 64 + ((q * 8) ^ ((t & 7) << 3))] = z;
    }
    __syncthreads();

    if (w < 5)
        compute_chunk(w, lane, 128, b, mask, sH, sWhi, sWlo, sW2,
                      &sH1[w * 4096], &sH1[w * 4096 + 2048],
                      cbias, b2s, W3s, b3v, ss);
    __syncthreads();

    float v = (tid < NT) ? ss[tid] : -3.0e38f;
    if (tid < 256) {
        float m = v;
#pragma unroll
        for (int o = 32; o; o >>= 1) m = fmaxf(m, __shfl_xor(m, o));
        if ((tid & 63) == 0) sred[tid >> 6] = m;
    }
    __syncthreads();
    const float M = fmaxf(fmaxf(sred[0], sred[1]), fmaxf(sred[2], sred[3]));
    float p = (tid < NT) ? __expf(v - M) : 0.f;
    if (tid < 256) {
        float s2 = p;
#pragma unroll
        for (int o = 32; o; o >>= 1) s2 += __shfl_xor(s2, o);
        if ((tid & 63) == 0) sred[4 + (tid >> 6)] = s2;
    }
    __syncthreads();
    const float S = sred[4] + sred[5] + sred[6] + sred[7];
    if (tid < NT) ss[tid] = p / S;
    __syncthreads();

    const int d = tid & 63, g = tid >> 6;
    float acc = 0.f;
    for (int t = g; t < NT; t += 8)
        acc = fmaf(ss[t], __bfloat162float(hp[((long)b * NT + t) * 64 + d]), acc);
    part[g * 65 + d] = acc;
    __syncthreads();
    if (tid < 64) {
        float o = 0.f;
#pragma unroll
        for (int g2 = 0; g2 < 8; g2++) o += part[g2 * 65 + tid];
        ((__hip_bfloat16*)out)[b * 64 + tid] = __float2bfloat16(o);
    }
}

// ===========================================================================
// f32 MFMA path — split-bf16 (hi/lo) 3-pass GEMMs on the matrix cores.
// h1 hi/lo buffers ALIAS the H staging buffer (uBuf); a barrier inside
// compute_chunk_f32 (after all waves load their A fragments) makes that safe.
// compute_chunk_f32 MUST be called by all 512 threads (it contains a barrier).
// ===========================================================================
__device__ __forceinline__ void compute_chunk_f32(
    int w, int lane, int tbase, int b, const int* mask,
    const __bf16* sHhi, const __bf16* sHlo,
    const __bf16* sWhi, const __bf16* sWlo,
    const __bf16* sW2h, const __bf16* sW2l,
    __bf16* h1hi, __bf16* h1lo,
    const float* cbias, const float* b2s, const float* W3s, float b3v,
    float* ss)
{
    const int lq = lane >> 4, lr = lane & 15;
    const int t0 = 16 * w;

    const int ar = t0 + lr;
    const int asw = (ar & 7) << 3;
    const bf16x8 a0h = *(const bf16x8*)&sHhi[ar * 64 + ((lq * 8) ^ asw)];
    const bf16x8 a1h = *(const bf16x8*)&sHhi[ar * 64 + ((32 + lq * 8) ^ asw)];
    const bf16x8 a0l = *(const bf16x8*)&sHlo[ar * 64 + ((lq * 8) ^ asw)];
    const bf16x8 a1l = *(const bf16x8*)&sHlo[ar * 64 + ((32 + lq * 8) ^ asw)];
    __syncthreads();  // after this, the H region may be overwritten by h1

    // GEMM1: 3-pass split (AhBh + AlBh + AhBl)
#pragma unroll
    for (int n = 0; n < 8; n++) {
        const int col = n * 16 + lr;
        const int bsw = (col & 7) << 3;
        const int wb = col * 64;
        const float cb = cbias[col];
        f32x4 c = {cb, cb, cb, cb};
        const bf16x8 bh0 = *(const bf16x8*)&sWhi[wb + ((lq * 8) ^ bsw)];
        const bf16x8 bh1 = *(const bf16x8*)&sWhi[wb + ((32 + lq * 8) ^ bsw)];
        const bf16x8 bl0 = *(const bf16x8*)&sWlo[wb + ((lq * 8) ^ bsw)];
        const bf16x8 bl1 = *(const bf16x8*)&sWlo[wb + ((32 + lq * 8) ^ bsw)];
        c = __builtin_amdgcn_mfma_f32_16x16x32_bf16(a0h, bh0, c, 0, 0, 0);
        c = __builtin_amdgcn_mfma_f32_16x16x32_bf16(a1h, bh1, c, 0, 0, 0);
        c = __builtin_amdgcn_mfma_f32_16x16x32_bf16(a0l, bh0, c, 0, 0, 0);
        c = __builtin_amdgcn_mfma_f32_16x16x32_bf16(a1l, bh1, c, 0, 0, 0);
        c = __builtin_amdgcn_mfma_f32_16x16x32_bf16(a0h, bl0, c, 0, 0, 0);
        c = __builtin_amdgcn_mfma_f32_16x16x32_bf16(a1h, bl1, c, 0, 0, 0);
#pragma unroll
        for (int r = 0; r < 4; r++) {
            const int row = lq * 4 + r;
            const int hoff = row * 128 + (col ^ ((row & 15) << 3));
            float v = fmaxf(c[r], 0.f);
            __bf16 hi = (__bf16)v;
            h1hi[hoff] = hi;
            h1lo[hoff] = (__bf16)(v - (float)hi);
        }
    }

    // GEMM2: 3-pass split (AhBh + AlBh + AhBl)
    f32x4 acc2[4];
#pragma unroll
    for (int n = 0; n < 4; n++) {
        const float bb = b2s[n * 16 + lr];
        acc2[n] = (f32x4){bb, bb, bb, bb};
    }
    const int a2sw = lr << 3;
#pragma unroll
    for (int s = 0; s < 4; s++) {
        const int k0 = s * 32 + lq * 8;
        const bf16x8 ah = *(const bf16x8*)&h1hi[lr * 128 + (k0 ^ a2sw)];
        const bf16x8 al = *(const bf16x8*)&h1lo[lr * 128 + (k0 ^ a2sw)];
#pragma unroll
        for (int n = 0; n < 4; n++) {
            const int col = n * 16 + lr;
            const int csw = (col & 15) << 3;
            const bf16x8 bh = *(const bf16x8*)&sW2h[col * 128 + (k0 ^ csw)];
            const bf16x8 bl = *(const bf16x8*)&sW2l[col * 128 + (k0 ^ csw)];
            acc2[n] = __builtin_amdgcn_mfma_f32_16x16x32_bf16(ah, bh, acc2[n], 0, 0, 0);
            acc2[n] = __builtin_amdgcn_mfma_f32_16x16x32_bf16(al, bh, acc2[n], 0, 0, 0);
            acc2[n] = __builtin_amdgcn_mfma_f32_16x16x32_bf16(ah, bl, acc2[n], 0, 0, 0);
        }
    }

    // scores
#pragma unroll
    for (int r = 0; r < 4; r++) {
        float p = 0.f;
#pragma unroll
        for (int n = 0; n < 4; n++)
            p = fmaf(fmaxf(acc2[n][r], 0.f), W3s[n * 16 + lr], p);
        p += __shfl_xor(p, 1);
        p += __shfl_xor(p, 2);
        p += __shfl_xor(p, 4);
        p += __shfl_xor(p, 8);
        const int gt = tbase + t0 + lq * 4 + r;
        if (lr == 0 && gt < NT)
            ss[gt] = (mask[(long)b * NT + gt] != 0) ? (p + b3v) : -1e9f;
    }
}

__global__ __launch_bounds__(512) void attn_f32_kernel(
    const void* cand, const void* hist, const int* mask,
    const int* flag_p, const float* F, void* out)
{
    if (flag_p[0] != 0) return;  // bf16 case handled by attn_bf16_kernel

    __shared__ __align__(16) __bf16 sWhi[8192];   // WeffT hi [128][64] swz
    __shared__ __align__(16) __bf16 sWlo[8192];   // WeffT lo
    __shared__ __align__(16) __bf16 sW2h[8192];   // W2T hi [64][128] swz
    __shared__ __align__(16) __bf16 sW2l[8192];   // W2T lo
    __shared__ __align__(16) __bf16 uBuf[32768];  // 64KB: H hi/lo (32KB) ∪ h1 (64KB)
    __shared__ float cbias[128];
    __shared__ float cs[64], W3s[64], b2s[64];
    __shared__ float ss[NT];
    __shared__ float sred[8];
    __shared__ float b3s;

    const int tid = threadIdx.x;
    const int b = blockIdx.x;
    const int w = tid >> 6, lane = tid & 63;
    const float* hf = (const float*)hist;

    __bf16* sHhi = uBuf;           // rows [0..127][64] swizzled
    __bf16* sHlo = uBuf + 8192;
    __bf16* h1hi = uBuf + w * 4096;      // per-wave [16][128] swz
    __bf16* h1lo = uBuf + w * 4096 + 2048;

    // ---- phase A: small loads, W2 hi/lo copy, stage chunk0 (rows 0..127) ----
    if (tid < 64) {
        cs[tid] = ((const float*)cand)[(long)b * 64 + tid];
        W3s[tid] = F[WS_W3 + tid];
        b2s[tid] = F[WS_B2 + tid];
    }
    if (tid == 0) b3s = F[WS_B3];
#pragma unroll
    for (int i = 0; i < 2; i++) {
        const int off = (tid + i * 512) * 16;
        *(uint4*)((char*)sW2h + off) = *(const uint4*)((const char*)g_w2tsh + off);
        *(uint4*)((char*)sW2l + off) = *(const uint4*)((const char*)g_w2tsl + off);
    }
#pragma unroll
    for (int i = 0; i < 4; i++) {
        const int e4 = tid + i * 512;          // float4 index, rows 0..127
        const int t = e4 >> 4, k = (e4 & 15) * 4;
        float4 v = *(const float4*)&hf[((long)b * NT + t) * 64 + k];
        bf16x4 hi4, lo4;
        hi4[0] = (__bf16)v.x; lo4[0] = (__bf16)(v.x - (float)hi4[0]);
        hi4[1] = (__bf16)v.y; lo4[1] = (__bf16)(v.y - (float)hi4[1]);
        hi4[2] = (__bf16)v.z; lo4[2] = (__bf16)(v.z - (float)hi4[2]);
        hi4[3] = (__bf16)v.w; lo4[3] = (__bf16)(v.w - (float)hi4[3]);
        const int pos = ((k & 56) ^ ((t & 7) << 3)) | (k & 4);
        *(bf16x4*)&sHhi[t * 64 + pos] = hi4;
        *(bf16x4*)&sHlo[t * 64 + pos] = lo4;
    }
    __syncthreads();

    // ---- phase B: Weff hi/lo, cbias, chunk1 register prefetch ----
#pragma unroll
    for (int i = 0; i < 16; i++) {
        const int e = tid + i * 512;
        const int j = e >> 6, k = e & 63;
        float wv = fmaf(cs[k], g_wdt[e], g_wxt[e]);
        __bf16 hi = (__bf16)wv;
        const int off = j * 64 + (k ^ ((j & 7) << 3));
        sWhi[off] = hi;
        sWlo[off] = (__bf16)(wv - (float)hi);
    }
    {
        const int j = tid >> 2, kq = (tid & 3) << 4;
        float a = 0.f;
#pragma unroll
        for (int k2 = 0; k2 < 16; k2++)
            a = fmaf(cs[kq + k2], F[WS_WC + (kq + k2) * 128 + j], a);
        a += __shfl_xor(a, 1);
        a += __shfl_xor(a, 2);
        if ((tid & 3) == 0) cbias[j] = a + F[WS_B1 + j];
    }
    // chunk1 (72 rows: local 0..71 = global 128..199) prefetch into registers
    float4 c1a0, c1a1, c1b = {0.f, 0.f, 0.f, 0.f};
    {
        int e4 = tid;
        int tl = e4 >> 4, k = (e4 & 15) * 4;
        c1a0 = *(const float4*)&hf[((long)b * NT + 128 + tl) * 64 + k];
        e4 = tid + 512;
        tl = e4 >> 4; k = (e4 & 15) * 4;
        c1a1 = *(const float4*)&hf[((long)b * NT + 128 + tl) * 64 + k];
    }
    if (tid < 128) {
        const int e4 = 1024 + tid;
        const int tl = e4 >> 4, k = (e4 & 15) * 4;
        c1b = *(const float4*)&hf[((long)b * NT + 128 + tl) * 64 + k];
    }
    __builtin_amdgcn_sched_barrier(0);
    __syncthreads();

    const float b3v = b3s;
    // ---- chunk 0: rows 0..127, all 8 waves ----
    compute_chunk_f32(w, lane, 0, b, mask, sHhi, sHlo, sWhi, sWlo, sW2h, sW2l,
                      h1hi, h1lo, cbias, b2s, W3s, b3v, ss);
    __syncthreads();  // all GEMM2 reads of h1 (uBuf) complete

    // ---- write chunk1 into sH (local rows 0..71, zero pad 72..79) ----
    {
        int e4 = tid;
        int tl = e4 >> 4, k = (e4 & 15) * 4;
        int pos = ((k & 56) ^ ((tl & 7) << 3)) | (k & 4);
        bf16x4 hi4, lo4;
        hi4[0] = (__bf16)c1a0.x; lo4[0] = (__bf16)(c1a0.x - (float)hi4[0]);
        hi4[1] = (__bf16)c1a0.y; lo4[1] = (__bf16)(c1a0.y - (float)hi4[1]);
        hi4[2] = (__bf16)c1a0.z; lo4[2] = (__bf16)(c1a0.z - (float)hi4[2]);
        hi4[3] = (__bf16)c1a0.w; lo4[3] = (__bf16)(c1a0.w - (float)hi4[3]);
        *(bf16x4*)&sHhi[tl * 64 + pos] = hi4;
        *(bf16x4*)&sHlo[tl * 64 + pos] = lo4;
        e4 = tid + 512;
        tl = e4 >> 4; k = (e4 & 15) * 4;
        pos = ((k & 56) ^ ((tl & 7) << 3)) | (k & 4);
        hi4[0] = (__bf16)c1a1.x; lo4[0] = (__bf16)(c1a1.x - (float)hi4[0]);
        hi4[1] = (__bf16)c1a1.y; lo4[1] = (__bf16)(c1a1.y - (float)hi4[1]);
        hi4[2] = (__bf16)c1a1.z; lo4[2] = (__bf16)(c1a1.z - (float)hi4[2]);
        hi4[3] = (__bf16)c1a1.w; lo4[3] = (__bf16)(c1a1.w - (float)hi4[3]);
        *(bf16x4*)&sHhi[tl * 64 + pos] = hi4;
        *(bf16x4*)&sHlo[tl * 64 + pos] = lo4;
    }
    if (tid < 128) {
        const int e4 = 1024 + tid;
        const int tl = e4 >> 4, k = (e4 & 15) * 4;
        const int pos = ((k & 56) ^ ((tl & 7) << 3)) | (k & 4);
        bf16x4 hi4, lo4;
        hi4[0] = (__bf16)c1b.x; lo4[0] = (__bf16)(c1b.x - (float)hi4[0]);
        hi4[1] = (__bf16)c1b.y; lo4[1] = (__bf16)(c1b.y - (float)hi4[1]);
        hi4[2] = (__bf16)c1b.z; lo4[2] = (__bf16)(c1b.z - (float)hi4[2]);
        hi4[3] = (__bf16)c1b.w; lo4[3] = (__bf16)(c1b.w - (float)hi4[3]);
        *(bf16x4*)&sHhi[tl * 64 + pos] = hi4;
        *(bf16x4*)&sHlo[tl * 64 + pos] = lo4;
    }
    if (tid < 128) {  // zero pad rows 72..79
        const int tl = 72 + (tid >> 4), k = (tid & 15) * 4;
        const int pos = ((k & 56) ^ ((tl & 7) << 3)) | (k & 4);
        bf16x4 z;
        z[0] = (__bf16)0.f; z[1] = (__bf16)0.f; z[2] = (__bf16)0.f; z[3] = (__bf16)0.f;
        *(bf16x4*)&sHhi[tl * 64 + pos] = z;
        *(bf16x4*)&sHlo[tl * 64 + pos] = z;
    }
    __syncthreads();

    // ---- chunk 1: rows 128..199; called by ALL waves (internal barrier).
    // Waves 5..7 compute garbage on stale LDS but all their stores are
    // range-guarded (gt >= 208 > NT) or land in their private h1 region.
    compute_chunk_f32(w, lane, 128, b, mask, sHhi, sHlo, sWhi, sWlo, sW2h, sW2l,
                      h1hi, h1lo, cbias, b2s, W3s, b3v, ss);
    __syncthreads();

    // ---- softmax over ss[0..199] ----
    float v = (tid < NT) ? ss[tid] : -3.0e38f;
    if (tid < 256) {
        float m = v;
#pragma unroll
        for (int o = 32; o; o >>= 1) m = fmaxf(m, __shfl_xor(m, o));
        if ((tid & 63) == 0) sred[tid >> 6] = m;
    }
    __syncthreads();
    const float M = fmaxf(fmaxf(sred[0], sred[1]), fmaxf(sred[2], sred[3]));
    float p = (tid < NT) ? __expf(v - M) : 0.f;
    if (tid < 256) {
        float s2 = p;
#pragma unroll
        for (int o = 32; o; o >>= 1) s2 += __shfl_xor(s2, o);
        if ((tid & 63) == 0) sred[4 + (tid >> 6)] = s2;
    }
    __syncthreads();
    const float S = sred[4] + sred[5] + sred[6] + sred[7];
    if (tid < NT) ss[tid] = p / S;
    __syncthreads();

    // ---- out[b][d] = sum_t w[t] * hist[b][t][d]; partials alias uBuf ----
    float* part = (float*)uBuf;  // 520 floats; uBuf dead by now
    const int d = tid & 63, g = tid >> 6;
    float acc = 0.f;
    for (int t = g; t < NT; t += 8)
        acc = fmaf(ss[t], hf[((long)b * NT + t) * 64 + d], acc);
    part[g * 65 + d] = acc;
    __syncthreads();
    if (tid < 64) {
        float o = 0.f;
#pragma unroll
        for (int g2 = 0; g2 < 8; g2++) o += part[g2 * 65 + tid];
        ((float*)out)[b * 64 + tid] = o;
    }
}

extern "C" void kernel_launch(void* const* d_in, const int* in_sizes, int n_in,
                              void* d_out, int out_size, void* d_ws, size_t ws_size,
                              hipStream_t stream) {
    const void* cand = d_in[0];
    const void* hist = d_in[1];
    const int* mask = (const int*)d_in[2];
    const void* W1 = d_in[3];
    const void* b1 = d_in[4];
    const void* W2 = d_in[5];
    const void* b2 = d_in[6];
    const void* W3 = d_in[7];
    const void* b3 = d_in[8];

    int* flag = (int*)d_ws;
    float* F = (float*)((char*)d_ws + 256);

    prep_kernel<<<32, 256, 0, stream>>>(W1, b1, W2, b2, W3, b3, flag, F);
    attn_f32_kernel<<<NB, 512, 0, stream>>>(cand, hist, mask, flag, F, d_out);
    attn_bf16_kernel<<<NB, 512, 0, stream>>>(cand, hist, mask, flag, F, d_out);
}